// Round 1
// 285.628 us; speedup vs baseline: 1.1448x; 1.1448x over previous
//
#include <hip/hip_runtime.h>

#define Hh 64
#define Ww 64
#define Cc 512
#define Bb 16
#define NTOK (1 + Hh * Ww)   // 4097
#define TW 8                 // outputs per thread along w
#define TH 8                 // outputs per thread along h

// ---------------------------------------------------------------------------
// Prep kernel (unchanged): combine w7 + padded w5 + padded w3 + identity into
// one effective 7x7 kernel per channel, stored TRANSPOSED [tap][channel] so
// conv-side tap reads are coalesced (lane = channel). Combine biases, copy
// cls tokens through.
// ---------------------------------------------------------------------------
__global__ void ppeg_prep(const float* __restrict__ w7, const float* __restrict__ b7,
                          const float* __restrict__ w5, const float* __restrict__ b5,
                          const float* __restrict__ w3, const float* __restrict__ b3,
                          const float* __restrict__ x, float* __restrict__ wt,
                          float* __restrict__ beff, float* __restrict__ out) {
    int idx = blockIdx.x * blockDim.x + threadIdx.x;
    if (idx < Cc * 49) {
        int c = idx / 49, t = idx % 49;
        int r = t / 7, s = t % 7;
        float v = w7[idx];
        if (r >= 1 && r <= 5 && s >= 1 && s <= 5) v += w5[c * 25 + (r - 1) * 5 + (s - 1)];
        if (r >= 2 && r <= 4 && s >= 2 && s <= 4) v += w3[c * 9 + (r - 2) * 3 + (s - 2)];
        if (t == 24) v += 1.0f;               // identity (center tap)
        wt[t * Cc + c] = v;                   // transposed store
    }
    if (idx < Cc) beff[idx] = b7[idx] + b5[idx] + b3[idx];
    if (idx < Bb * Cc) {
        int b = idx / Cc, c = idx % Cc;
        size_t o = (size_t)b * NTOK * Cc + c;
        out[o] = x[o];                        // cls token pass-through
    }
}

// ---------------------------------------------------------------------------
// Conv kernel v2: input-row streaming with fat threads.
//
// Previous version (32 VGPR, 2x8 tile, r-outer loop) was latency-bound:
// burst 14 loads -> drain -> 112 FMA cycles, no register headroom to
// prefetch (VALUBusy 32%, HBM 35%). This version:
//   - thread owns an 8x8 output tile; streams 14 input rows, each loaded
//     ONCE and applied to every output row it feeds (~350 FMA per 14-load
//     burst vs 56 before) -> per-wave compute covers HBM latency.
//   - all 49 combined taps live in VGPRs (one L1-hot read each at start).
//   - __launch_bounds__(256,2): cap 256 VGPR (expect ~160-190), giving the
//     scheduler free registers to pipeline the next row's loads. Occupancy
//     drops to 8 waves/CU BY DESIGN; ILP replaces TLP.
//   - block = 32h x 8w x 64ch; grid.x = wblk + 8*hblk so the two h-blocks
//     of a column map to the SAME XCD (x, x+8) -> h-halo re-reads hit L2.
//   - non-temporal output stores: 134 MB of writes no longer evict the
//     input from L3, so w-halo re-reads across blocks stay L3-resident.
// ---------------------------------------------------------------------------
__global__ __launch_bounds__(256, 2)
void ppeg_conv(const float* __restrict__ x, const float* __restrict__ wt,
               const float* __restrict__ beff, float* __restrict__ out) {
    const int tx = threadIdx.x;        // channel lane 0..63
    const int ty = threadIdx.y;        // h-subtile 0..3 (wave-uniform)
    const int c  = blockIdx.y * 64 + tx;
    const int b  = blockIdx.z;
    const int wblk = blockIdx.x & 7;   // 0..7
    const int hblk = blockIdx.x >> 3;  // 0..1
    const int oh0   = hblk * 32 + ty * TH;   // first of TH output rows
    const int wbase = wblk * TW;

    const float* xb = x + ((size_t)b * NTOK + 1) * Cc + c;   // pixel (0,0), ch c

    // All 49 effective taps in registers; slab is 12.5 KB/64ch -> L1-hot.
    float tap[49];
#pragma unroll
    for (int t = 0; t < 49; ++t) tap[t] = wt[t * Cc + c];

    const float bias = beff[c];
    float acc[TH][TW];
#pragma unroll
    for (int o = 0; o < TH; ++o)
#pragma unroll
        for (int j = 0; j < TW; ++j) acc[o][j] = bias;

    const bool interior = (wblk != 0) && (wblk != 7);

    // Stream input rows ir = oh0-3 .. oh0+TH+2. Row k feeds output rows
    // o in [k-6, k] (tap row r = k-o). All indices compile-time after unroll.
#pragma unroll
    for (int k = 0; k < TH + 6; ++k) {
        const int ir = oh0 + k - 3;
        if (ir >= 0 && ir < Hh) {              // wave-uniform (oh0 fixed/wave)
            const float* xrow = xb + (size_t)ir * (Ww * Cc);
            float v[TW + 6];
            if (interior) {
#pragma unroll
                for (int j = 0; j < TW + 6; ++j)
                    v[j] = xrow[(size_t)(wbase - 3 + j) * Cc];
            } else {
#pragma unroll
                for (int j = 0; j < TW + 6; ++j) {
                    const int wc = wbase + j - 3;
                    v[j] = (wc >= 0 && wc < Ww) ? xrow[(size_t)wc * Cc] : 0.0f;
                }
            }
#pragma unroll
            for (int o = 0; o < TH; ++o) {
                if (o > k || o < k - 6) continue;   // static after unroll
                const int r = k - o;
#pragma unroll
                for (int s = 0; s < 7; ++s) {
                    const float tp = tap[r * 7 + s];
#pragma unroll
                    for (int j = 0; j < TW; ++j)
                        acc[o][j] = fmaf(tp, v[j + s], acc[o][j]);
                }
            }
        }
    }

#pragma unroll
    for (int o = 0; o < TH; ++o) {
        float* orow = out + ((size_t)b * NTOK + 1 + (size_t)(oh0 + o) * Ww + wbase) * Cc + c;
#pragma unroll
        for (int j = 0; j < TW; ++j)
            __builtin_nontemporal_store(acc[o][j], &orow[(size_t)j * Cc]);
    }
}

extern "C" void kernel_launch(void* const* d_in, const int* in_sizes, int n_in,
                              void* d_out, int out_size, void* d_ws, size_t ws_size,
                              hipStream_t stream) {
    const float* x  = (const float*)d_in[0];
    const float* w7 = (const float*)d_in[1];
    const float* b7 = (const float*)d_in[2];
    const float* w5 = (const float*)d_in[3];
    const float* b5 = (const float*)d_in[4];
    const float* w3 = (const float*)d_in[5];
    const float* b3 = (const float*)d_in[6];
    float* out = (float*)d_out;

    float* wt   = (float*)d_ws;          // 49*Cc floats, transposed [tap][channel]
    float* beff = wt + 49 * Cc;          // Cc floats

    ppeg_prep<<<(Cc * 49 + 255) / 256, 256, 0, stream>>>(w7, b7, w5, b5, w3, b3,
                                                         x, wt, beff, out);

    // grid.x: wblk fast (0..7), hblk slow (0..1) -> column pair on same XCD
    dim3 grid(16, Cc / 64, Bb);          // (16, 8, 16) = 2048 blocks
    dim3 block(64, 4);
    ppeg_conv<<<grid, block, 0, stream>>>(x, wt, beff, out);
}